// Round 5
// baseline (4067.268 us; speedup 1.0000x reference)
//
#include <hip/hip_runtime.h>
#include <math.h>

// Problem constants (fixed by setup_inputs): B=16, T=4096, D=512, fp32.
#define BB 16
#define TT 4096
#define DD 512
#define D4 128              // DD / 4 (float4 columns)

constexpr int CCF = 128;        // chunks along T (fused path)
constexpr int LLF = TT / CCF;   // 32 steps per chunk
constexpr int CC  = 256;        // fallback 3-kernel decomposition
constexpr int LL  = TT / CC;

// Flag magics: must not equal the 0xAAAAAAAA workspace poison.
constexpr unsigned MAGIC_A = 0x0B0B0B01u;   // aggregate published
constexpr unsigned MAGIC_I = 0x0B0B0B02u;   // inclusive published

typedef float floatx4 __attribute__((ext_vector_type(4)));

__device__ __forceinline__ float sigmf(float v) {
    return 1.0f / (1.0f + expf(-v));
}

// ===========================================================================
// Single-launch domino kernel (decoupled carry propagation, rocPRIM-style).
// Grid: 1024 blocks = 8 b-pairs x 128 chunks; blockIdx.x = bp*128 + c, so all
// spin-wait dependencies point to strictly lower block IDs. With
// __launch_bounds__(256,4) all 1024 blocks are co-resident (4/CU x 256 CU).
// ===========================================================================
__global__ __launch_bounds__(256, 4) void es_domino(
    const float* __restrict__ x, const float* __restrict__ alpha,
    float* __restrict__ aggr,      // [BB][CCF][D4] float4: chunk aggregates
    float* __restrict__ incl,      // [BB][CCF][D4] float4: inclusive carries
    unsigned* __restrict__ flags,  // [8*CCF] one per block
    float* __restrict__ out)
{
    const int tid = threadIdx.x;
    const int c   = blockIdx.x & (CCF - 1);
    const int bp  = blockIdx.x >> 7;           // b-pair 0..7
    const int b   = (bp << 1) + (tid >> 7);
    const int d4  = tid & 127;

    const float4 al = reinterpret_cast<const float4*>(alpha)[d4];
    const float ax = sigmf(al.x), ay = sigmf(al.y), az = sigmf(al.z), aw = sigmf(al.w);
    const float fx = 1.0f - ax, fy = 1.0f - ay, fz = 1.0f - az, fw = 1.0f - aw;

    const size_t base = ((size_t)b * TT + (size_t)c * LLF) * D4 + d4;
    const size_t slot = ((size_t)b * CCF + c) * D4 + d4;      // float4 units

    // ---- Phase 1: local chunk scan (zero init; chunk 0 exact).
    float4 s;
    {
        const float4* xp = reinterpret_cast<const float4*>(x) + base;
        constexpr int W = 8;
        float4 w[W];
        #pragma unroll
        for (int j = 0; j < W; ++j) w[j] = xp[(size_t)j * D4];
        if (c == 0) s = w[0];                  // virtual s_{-1} = x_0
        else        { s.x = s.y = s.z = s.w = 0.0f; }
        #pragma unroll
        for (int i = 0; i < LLF; ++i) {
            const float4 v = w[i & (W - 1)];
            if (i + W < LLF) w[i & (W - 1)] = xp[(size_t)(i + W) * D4];
            s.x = fmaf(ax, v.x, fx * s.x);
            s.y = fmaf(ay, v.y, fy * s.y);
            s.z = fmaf(az, v.z, fz * s.z);
            s.w = fmaf(aw, v.w, fw * s.w);
        }
    }

    // ---- Publish aggregate (chunk 0 publishes directly as inclusive).
    {
        float* dst = (c == 0 ? incl : aggr) + slot * 4;
        __hip_atomic_store(dst + 0, s.x, __ATOMIC_RELAXED, __HIP_MEMORY_SCOPE_AGENT);
        __hip_atomic_store(dst + 1, s.y, __ATOMIC_RELAXED, __HIP_MEMORY_SCOPE_AGENT);
        __hip_atomic_store(dst + 2, s.z, __ATOMIC_RELAXED, __HIP_MEMORY_SCOPE_AGENT);
        __hip_atomic_store(dst + 3, s.w, __ATOMIC_RELAXED, __HIP_MEMORY_SCOPE_AGENT);
        __syncthreads();   // all payload stores issued before the flag
        if (tid == 0) {
            __hip_atomic_store(&flags[blockIdx.x], (c == 0 ? MAGIC_I : MAGIC_A),
                               __ATOMIC_RELEASE, __HIP_MEMORY_SCOPE_AGENT);
        }
    }

    if (c == 0) {
        // ---- Scanner: fold aggregates 1..CCF-1 into inclusives (this b-pair).
        float4 fL;
        fL.x = powf(fx, (float)LLF);
        fL.y = powf(fy, (float)LLF);
        fL.z = powf(fz, (float)LLF);
        fL.w = powf(fw, (float)LLF);

        unsigned* flg = flags + (bp << 7);
        float4 S = s;                          // inclusive of chunk 0
        for (int ww = 1; ww < CCF; ww += 8) {
            const int n = (CCF - ww < 8) ? (CCF - ww) : 8;
            // Wait until the whole window's aggregates are published.
            bool ok = false;
            while (!ok) {
                ok = true;
                #pragma unroll
                for (int j = 0; j < 8; ++j) {
                    if (j < n) {
                        unsigned f = __hip_atomic_load(&flg[ww + j], __ATOMIC_ACQUIRE,
                                                       __HIP_MEMORY_SCOPE_AGENT);
                        ok &= (f == MAGIC_A);
                    }
                }
                if (!ok) __builtin_amdgcn_s_sleep(2);
            }
            // Batch-load payloads (independent -> pipelined).
            float4 E[8];
            #pragma unroll
            for (int j = 0; j < 8; ++j) {
                if (j < n) {
                    float* src = aggr + (((size_t)b * CCF + ww + j) * D4 + d4) * 4;
                    E[j].x = __hip_atomic_load(src + 0, __ATOMIC_RELAXED, __HIP_MEMORY_SCOPE_AGENT);
                    E[j].y = __hip_atomic_load(src + 1, __ATOMIC_RELAXED, __HIP_MEMORY_SCOPE_AGENT);
                    E[j].z = __hip_atomic_load(src + 2, __ATOMIC_RELAXED, __HIP_MEMORY_SCOPE_AGENT);
                    E[j].w = __hip_atomic_load(src + 3, __ATOMIC_RELAXED, __HIP_MEMORY_SCOPE_AGENT);
                }
            }
            // Sequential fold + publish inclusives.
            #pragma unroll
            for (int j = 0; j < 8; ++j) {
                if (j < n) {
                    S.x = fmaf(fL.x, S.x, E[j].x);
                    S.y = fmaf(fL.y, S.y, E[j].y);
                    S.z = fmaf(fL.z, S.z, E[j].z);
                    S.w = fmaf(fL.w, S.w, E[j].w);
                    float* dst = incl + (((size_t)b * CCF + ww + j) * D4 + d4) * 4;
                    __hip_atomic_store(dst + 0, S.x, __ATOMIC_RELAXED, __HIP_MEMORY_SCOPE_AGENT);
                    __hip_atomic_store(dst + 1, S.y, __ATOMIC_RELAXED, __HIP_MEMORY_SCOPE_AGENT);
                    __hip_atomic_store(dst + 2, S.z, __ATOMIC_RELAXED, __HIP_MEMORY_SCOPE_AGENT);
                    __hip_atomic_store(dst + 3, S.w, __ATOMIC_RELAXED, __HIP_MEMORY_SCOPE_AGENT);
                }
            }
            __syncthreads();
            if (tid == 0) {
                #pragma unroll
                for (int j = 0; j < 8; ++j) {
                    if (j < n)
                        __hip_atomic_store(&flg[ww + j], MAGIC_I,
                                           __ATOMIC_RELEASE, __HIP_MEMORY_SCOPE_AGENT);
                }
            }
        }
    } else {
        // ---- Wait for predecessor's inclusive carry.
        const unsigned fidx = (unsigned)(bp << 7) + c - 1;
        while (__hip_atomic_load(&flags[fidx], __ATOMIC_ACQUIRE,
                                 __HIP_MEMORY_SCOPE_AGENT) != MAGIC_I)
            __builtin_amdgcn_s_sleep(4);
        float* src = incl + (((size_t)b * CCF + (c - 1)) * D4 + d4) * 4;
        s.x = __hip_atomic_load(src + 0, __ATOMIC_RELAXED, __HIP_MEMORY_SCOPE_AGENT);
        s.y = __hip_atomic_load(src + 1, __ATOMIC_RELAXED, __HIP_MEMORY_SCOPE_AGENT);
        s.z = __hip_atomic_load(src + 2, __ATOMIC_RELAXED, __HIP_MEMORY_SCOPE_AGENT);
        s.w = __hip_atomic_load(src + 3, __ATOMIC_RELAXED, __HIP_MEMORY_SCOPE_AGENT);
    }

    // ---- Phase 3: reload x (L2/L3-hot), scan from exact carry, NT-store out.
    {
        const float4* xp = reinterpret_cast<const float4*>(x) + base;
        asm volatile("" : "+v"(xp));   // block CSE of phase-1 loads across phases
        floatx4* op = reinterpret_cast<floatx4*>(out) + base;

        constexpr int W = 8;
        float4 w[W];
        #pragma unroll
        for (int j = 0; j < W; ++j) w[j] = xp[(size_t)j * D4];
        if (c == 0) s = w[0];          // s_{-1} = x_0 (s was clobbered by scan)

        #pragma unroll
        for (int i = 0; i < LLF; ++i) {
            const float4 v = w[i & (W - 1)];
            if (i + W < LLF) w[i & (W - 1)] = xp[(size_t)(i + W) * D4];
            s.x = fmaf(ax, v.x, fx * s.x);
            s.y = fmaf(ay, v.y, fy * s.y);
            s.z = fmaf(az, v.z, fz * s.z);
            s.w = fmaf(aw, v.w, fw * s.w);
            floatx4 sv = { s.x, s.y, s.z, s.w };
            __builtin_nontemporal_store(sv, op + (size_t)i * D4);
        }
    }
}

// ===========================================================================
// Fallback 3-kernel path (ws too small for the domino buffers).
// ===========================================================================
__global__ __launch_bounds__(256) void es_chunk_ends(
    const float* __restrict__ x, const float* __restrict__ alpha,
    float* __restrict__ ends)
{
    const int c   = blockIdx.x;
    const int tid = threadIdx.x;
    const int b   = (blockIdx.y << 1) + (tid >> 7);
    const int d4  = tid & 127;

    const float4* xp = reinterpret_cast<const float4*>(x)
                     + ((size_t)b * TT + (size_t)c * LL) * D4 + d4;

    float4 v[LL];
    #pragma unroll
    for (int i = 0; i < LL; ++i) v[i] = xp[(size_t)i * D4];

    const float4 al = reinterpret_cast<const float4*>(alpha)[d4];
    const float ax = sigmf(al.x), ay = sigmf(al.y), az = sigmf(al.z), aw = sigmf(al.w);
    const float fx = 1.0f - ax, fy = 1.0f - ay, fz = 1.0f - az, fw = 1.0f - aw;

    float4 s;
    if (c == 0) s = v[0];
    else        { s.x = s.y = s.z = s.w = 0.0f; }

    #pragma unroll
    for (int i = 0; i < LL; ++i) {
        s.x = fmaf(ax, v[i].x, fx * s.x);
        s.y = fmaf(ay, v[i].y, fy * s.y);
        s.z = fmaf(az, v[i].z, fz * s.z);
        s.w = fmaf(aw, v[i].w, fw * s.w);
    }
    reinterpret_cast<float4*>(ends)[((size_t)b * CC + c) * D4 + d4] = s;
}

__global__ __launch_bounds__(256) void es_carry_scan(
    float* __restrict__ ends, const float* __restrict__ alpha)
{
    const int g  = blockIdx.x * 256 + threadIdx.x;
    const int b  = g >> 7;
    const int d4 = g & 127;

    const float4 al = reinterpret_cast<const float4*>(alpha)[d4];
    float4 fL;
    fL.x = powf(1.0f - sigmf(al.x), (float)LL);
    fL.y = powf(1.0f - sigmf(al.y), (float)LL);
    fL.z = powf(1.0f - sigmf(al.z), (float)LL);
    fL.w = powf(1.0f - sigmf(al.w), (float)LL);

    float4* e = reinterpret_cast<float4*>(ends) + (size_t)b * CC * D4 + d4;

    constexpr int P = 16;
    float4 buf[P];
    #pragma unroll
    for (int j = 0; j < P; ++j) buf[j] = e[(size_t)(1 + j) * D4];

    float4 S = e[0];
    int c = 1;
    while (c + P <= CC) {
        #pragma unroll
        for (int j = 0; j < P; ++j) {
            const float4 v = buf[j];
            const int pf = c + P;
            if (pf < CC) buf[j] = e[(size_t)pf * D4];
            S.x = fmaf(fL.x, S.x, v.x);
            S.y = fmaf(fL.y, S.y, v.y);
            S.z = fmaf(fL.z, S.z, v.z);
            S.w = fmaf(fL.w, S.w, v.w);
            e[(size_t)c * D4] = S;
            ++c;
        }
    }
    for (int j = 0; c < CC; ++c, ++j) {
        const float4 v = buf[j];
        S.x = fmaf(fL.x, S.x, v.x);
        S.y = fmaf(fL.y, S.y, v.y);
        S.z = fmaf(fL.z, S.z, v.z);
        S.w = fmaf(fL.w, S.w, v.w);
        e[(size_t)c * D4] = S;
    }
}

__global__ __launch_bounds__(256) void es_final(
    const float* __restrict__ x, const float* __restrict__ alpha,
    const float* __restrict__ carries, float* __restrict__ out)
{
    const int c   = blockIdx.x;
    const int tid = threadIdx.x;
    const int b   = (blockIdx.y << 1) + (tid >> 7);
    const int d4  = tid & 127;

    float4 s;
    if (c != 0) {
        s = reinterpret_cast<const float4*>(carries)[((size_t)b * CC + (c - 1)) * D4 + d4];
    }

    const size_t base = ((size_t)b * TT + (size_t)c * LL) * D4 + d4;
    const float4* xp = reinterpret_cast<const float4*>(x) + base;
    floatx4*      op = reinterpret_cast<floatx4*>(out) + base;

    float4 v[LL];
    #pragma unroll
    for (int i = 0; i < LL; ++i) v[i] = xp[(size_t)i * D4];

    const float4 al = reinterpret_cast<const float4*>(alpha)[d4];
    const float ax = sigmf(al.x), ay = sigmf(al.y), az = sigmf(al.z), aw = sigmf(al.w);
    const float fx = 1.0f - ax, fy = 1.0f - ay, fz = 1.0f - az, fw = 1.0f - aw;

    if (c == 0) s = v[0];

    #pragma unroll
    for (int i = 0; i < LL; ++i) {
        s.x = fmaf(ax, v[i].x, fx * s.x);
        s.y = fmaf(ay, v[i].y, fy * s.y);
        s.z = fmaf(az, v[i].z, fz * s.z);
        s.w = fmaf(aw, v[i].w, fw * s.w);
        floatx4 sv = { s.x, s.y, s.z, s.w };
        __builtin_nontemporal_store(sv, op + (size_t)i * D4);
    }
}

extern "C" void kernel_launch(void* const* d_in, const int* in_sizes, int n_in,
                              void* d_out, int out_size, void* d_ws, size_t ws_size,
                              hipStream_t stream)
{
    const float* x     = (const float*)d_in[0];
    const float* alpha = (const float*)d_in[1];
    float*       out   = (float*)d_out;

    // Domino layout in ws: aggr (4 MiB) | incl (4 MiB) | flags (4 KiB).
    const size_t aggr_sz  = (size_t)BB * CCF * DD * sizeof(float);
    const size_t flags_sz = (size_t)(BB / 2) * CCF * sizeof(unsigned);
    if (ws_size >= 2 * aggr_sz + flags_sz) {
        float*    aggr  = (float*)d_ws;
        float*    incl  = (float*)((char*)d_ws + aggr_sz);
        unsigned* flags = (unsigned*)((char*)d_ws + 2 * aggr_sz);
        es_domino<<<dim3((BB / 2) * CCF), 256, 0, stream>>>(
            x, alpha, aggr, incl, flags, out);
        return;
    }

    // Fallback: 3-kernel pipeline.
    const size_t need = (size_t)BB * CC * DD * sizeof(float);
    if (ws_size >= need) {
        float* ends = (float*)d_ws;
        es_chunk_ends<<<dim3(CC, BB / 2), 256, 0, stream>>>(x, alpha, ends);
        es_carry_scan<<<dim3(8), 256, 0, stream>>>(ends, alpha);
        es_final<<<dim3(CC, BB / 2), 256, 0, stream>>>(x, alpha, ends, out);
    }
}

// Round 6
// 293.353 us; speedup vs baseline: 13.8648x; 13.8648x over previous
//
#include <hip/hip_runtime.h>
#include <math.h>

// Problem constants (fixed by setup_inputs): B=16, T=4096, D=512, fp32.
#define BB 16
#define TT 4096
#define DD 512
#define D4 128               // DD / 4 (float4 columns)

constexpr int G   = 4;        // float4 columns per block (64 B contiguous / 4 lanes)
constexpr int NC  = 64;       // t-chunks per block (threads = G * NC = 256)
constexpr int LCH = TT / NC;  // 64 steps per thread-chunk

typedef float floatx4 __attribute__((ext_vector_type(4)));

__device__ __forceinline__ float sigmf(float v) {
    return 1.0f / (1.0f + expf(-v));
}

// ===========================================================================
// Single-launch, zero-cross-block-sync scan.
// Block = (b, 4-float4-column group) covering ALL of T. 256 threads =
// 64 t-chunks x 4 columns; tid = tc*4 + g so 4 consecutive lanes read 64 B
// contiguous (one sector), then jump L*2KB.
//   Phase A: per-thread zero-init local scan over L=64 (chunk 0 exact).
//   Phase B: Kogge-Stone inclusive scan of the 64 chunk-ends in LDS.
//            Uniform chunk length => step decay factor is f^(L*2^k),
//            maintained by repeated squaring. 6 steps, __syncthreads only.
//   Phase C: re-stream x (stripe is L2/L3-hot from phase A), scan from the
//            exact carry, non-temporal store to out.
// Lesson from R4/R5: grid.sync ~100us, agent-scope spin chains ~ms on
// 8-XCD MI355X. Everything here is intra-block.
// ===========================================================================
__global__ __launch_bounds__(256) void es_block(
    const float* __restrict__ x, const float* __restrict__ alpha,
    float* __restrict__ out)
{
    const int tid = threadIdx.x;
    const int g   = tid & (G - 1);
    const int tc  = tid >> 2;             // t-chunk index 0..63
    const int b   = blockIdx.x >> 5;      // 32 column-groups per b
    const int grp = blockIdx.x & 31;
    const int d4  = (grp << 2) + g;       // this thread's float4 column

    const float4 al = reinterpret_cast<const float4*>(alpha)[d4];
    const float ax = sigmf(al.x), ay = sigmf(al.y), az = sigmf(al.z), aw = sigmf(al.w);
    const float fx = 1.0f - ax, fy = 1.0f - ay, fz = 1.0f - az, fw = 1.0f - aw;

    const size_t base = ((size_t)b * TT + (size_t)tc * LCH) * D4 + d4;
    const float4* xp = reinterpret_cast<const float4*>(x) + base;

    // ---- Phase A: local zero-init scan (chunk 0: exact s_{-1} = x_0).
    float4 s;
    {
        constexpr int W = 8;              // rolling load window
        float4 w[W];
        #pragma unroll
        for (int j = 0; j < W; ++j) w[j] = xp[(size_t)j * D4];
        if (tc == 0) s = w[0];
        else         { s.x = s.y = s.z = s.w = 0.0f; }
        #pragma unroll
        for (int i = 0; i < LCH; ++i) {
            const float4 v = w[i & (W - 1)];
            if (i + W < LCH) w[i & (W - 1)] = xp[(size_t)(i + W) * D4];
            s.x = fmaf(ax, v.x, fx * s.x);
            s.y = fmaf(ay, v.y, fy * s.y);
            s.z = fmaf(az, v.z, fz * s.z);
            s.w = fmaf(aw, v.w, fw * s.w);
        }
    }

    // ---- Phase B: Kogge-Stone inclusive scan over the NC chunk-ends.
    __shared__ float4 Eb[256];            // 4 KiB
    // fp = f^LCH per component (6 squarings: LCH = 64).
    float4 fp;
    fp.x = fx; fp.y = fy; fp.z = fz; fp.w = fw;
    #pragma unroll
    for (int k = 0; k < 6; ++k) {
        fp.x *= fp.x; fp.y *= fp.y; fp.z *= fp.z; fp.w *= fp.w;
    }

    float4 S = s;
    Eb[tid] = S;
    #pragma unroll
    for (int off = 1; off < NC; off <<= 1) {
        __syncthreads();
        float4 Sp;
        const bool act = (tc >= off);
        if (act) Sp = Eb[tid - off * G];
        __syncthreads();
        if (act) {
            S.x = fmaf(fp.x, Sp.x, S.x);
            S.y = fmaf(fp.y, Sp.y, S.y);
            S.z = fmaf(fp.z, Sp.z, S.z);
            S.w = fmaf(fp.w, Sp.w, S.w);
        }
        Eb[tid] = S;
        fp.x *= fp.x; fp.y *= fp.y; fp.z *= fp.z; fp.w *= fp.w;
    }
    __syncthreads();

    // Exclusive carry for this chunk = inclusive S of chunk tc-1.
    float4 carry;
    if (tc > 0) carry = Eb[tid - G];

    // ---- Phase C: re-stream x (L2/L3-hot), exact scan, NT-store out.
    {
        const float4* xq = xp;
        asm volatile("" : "+v"(xq));      // block CSE of phase-A loads
        floatx4* op = reinterpret_cast<floatx4*>(out) + base;

        constexpr int W = 8;
        float4 w[W];
        #pragma unroll
        for (int j = 0; j < W; ++j) w[j] = xq[(size_t)j * D4];

        float4 t;
        if (tc == 0) t = w[0];            // s_{-1} = x_0
        else         t = carry;

        #pragma unroll
        for (int i = 0; i < LCH; ++i) {
            const float4 v = w[i & (W - 1)];
            if (i + W < LCH) w[i & (W - 1)] = xq[(size_t)(i + W) * D4];
            t.x = fmaf(ax, v.x, fx * t.x);
            t.y = fmaf(ay, v.y, fy * t.y);
            t.z = fmaf(az, v.z, fz * t.z);
            t.w = fmaf(aw, v.w, fw * t.w);
            floatx4 sv = { t.x, t.y, t.z, t.w };
            __builtin_nontemporal_store(sv, op + (size_t)i * D4);
        }
    }
}

extern "C" void kernel_launch(void* const* d_in, const int* in_sizes, int n_in,
                              void* d_out, int out_size, void* d_ws, size_t ws_size,
                              hipStream_t stream)
{
    const float* x     = (const float*)d_in[0];
    const float* alpha = (const float*)d_in[1];
    float*       out   = (float*)d_out;
    (void)d_ws; (void)ws_size;

    // 512 blocks = 16 b x 32 column-groups; no workspace, no cross-block sync.
    es_block<<<dim3(BB * 32), 256, 0, stream>>>(x, alpha, out);
}